// Round 17
// baseline (52.063 us; speedup 1.0000x reference)
//
#include <hip/hip_runtime.h>

typedef __attribute__((ext_vector_type(8))) short short8;   // 8 bf16 (4 VGPR)
typedef __attribute__((ext_vector_type(4))) float f32x4;    // MFMA C/D
typedef __attribute__((ext_vector_type(2))) float f32x2;    // packed fp32 (v_pk_*)
typedef __attribute__((ext_vector_type(4))) int int4v;

#define CHUNK 1024
#define NBINS 32
#define NCLS  10
#define NREP  8

__global__ __launch_bounds__(256) void dvh_main(
    const float* __restrict__ pred, const float* __restrict__ targ,
    const float* __restrict__ mask, float* __restrict__ gD, float* __restrict__ gN,
    int chunksPerN)
{
    __shared__ float2 sE[CHUNK];                 // (Ep,Et) per voxel, 8 KB
    __shared__ unsigned short mT[NCLS * CHUNK];  // bf16 masks [10][1024] swizzled, 20 KB

    const int tid  = threadIdx.x;
    const int lane = tid & 63;
    const int w    = tid >> 6;       // wave 0..3
    const int n15  = lane & 15;      // MFMA row/col index
    const int g    = lane >> 4;      // k-group 0..3

    const int chunk = blockIdx.x;
    const size_t vbase = (size_t)chunk * CHUNK;

    // ---- issue ALL global loads first (latency overlaps across blocks) ----
    float4 p = ((const float4*)(pred + vbase))[tid];     // voxels 4t..4t+3
    float4 t = ((const float4*)(targ + vbase))[tid];
    uint4 mv[10];
    {
        const uint4* m4g = (const uint4*)(mask + vbase * NCLS);
        #pragma unroll
        for (int k = 0; k < 10; ++k) mv[k] = m4g[k * 256 + tid];
    }

    const float K1 = __expf((float)n15);        // e^bin, bins 0..15
    const float K2 = K1 * 8886110.5f;           // * e^16 -> bins 16..31

    // ---- stage doses: exp once per voxel ----
    *(float4*)&sE[4 * tid]     = make_float4(__expf(-32.f * p.x), __expf(-32.f * t.x),
                                             __expf(-32.f * p.y), __expf(-32.f * t.y));
    *(float4*)&sE[4 * tid + 2] = make_float4(__expf(-32.f * p.z), __expf(-32.f * t.z),
                                             __expf(-32.f * p.w), __expf(-32.f * t.w));
    // ---- stage masks: 0/1 f32 -> bf16 (top 16 bits), swizzled transpose ----
    {
        int f0 = tid * 4;
        int vv = f0 / 10;
        int cc = f0 - vv * 10;
        #pragma unroll
        for (int k = 0; k < 10; ++k) {
            unsigned int e[4] = {mv[k].x, mv[k].y, mv[k].z, mv[k].w};
            #pragma unroll
            for (int q = 0; q < 4; ++q) {
                mT[cc * CHUNK + (((vv >> 3) ^ (cc & 7)) << 3) + (vv & 7)] =
                    (unsigned short)(e[q] >> 16);
                cc += 1;
                int wrap = (cc >= 10);
                cc -= wrap * 10;
                vv += wrap;
            }
            vv += 102;   // k-stride 1024 floats = 102*10 + 4
        }
    }
    __syncthreads();

    f32x4 acc1 = {0,0,0,0};          // bins 0-15
    f32x4 acc2 = {0,0,0,0};          // bins 16-31
    f32x4 cnt  = {0,0,0,0};          // voxel counts
    short8 ones;
    #pragma unroll
    for (int i = 0; i < 8; ++i) ones[i] = (short)0x3F80;   // bf16 1.0
    const f32x2 one2 = {1.f, 1.f};

    // B-row: lanes n15>=10 have no class; read row n15-10 (junk-but-valid,
    // feeds only MFMA output columns 10..15, which are never consumed).
    const int brow = (n15 < NCLS) ? n15 : (n15 - NCLS);

    #pragma unroll
    for (int st = 0; st < 8; ++st) {
        const int vb = (w * 8 + st) * 32;    // this wave's 32-voxel K-block
        const int v0 = vb + g * 8;           // this lane's 8 voxels
        short8 fb = *(const short8*)&mT[brow * CHUNK + (((v0 >> 3) ^ (brow & 7)) << 3)];
        const float4* e4 = (const float4*)&sE[v0];

        int u1[4], u2[4];
        #pragma unroll
        for (int j = 0; j < 4; ++j) {
            float4 q = e4[j];                 // (Epa, Eta, Epb, Etb)
            f32x2 ep = {q.x, q.z};
            f32x2 et = {q.y, q.w};
            f32x2 de = et - ep;               // v_pk_add (sub)
            {   // K1: packed denominators, one rcp per voxel pair
                f32x2 Kv = {K1, K1};
                f32x2 u  = __builtin_elementwise_fma(ep, Kv, one2);
                f32x2 v  = __builtin_elementwise_fma(et, Kv, one2);
                f32x2 pr = u * v;             // (pa, pb)
                float rD = __builtin_amdgcn_rcpf(pr.x * pr.y);
                f32x2 sw = {pr.y, pr.x};
                f32x2 s  = (de * Kv) * (sw * rD);   // (sa, sb)
                unsigned h1;
                asm("v_cvt_pk_bf16_f32 %0, %1, %2" : "=v"(h1) : "v"(s.x), "v"(s.y));
                u1[j] = (int)h1;
            }
            {   // K2
                f32x2 Kv = {K2, K2};
                f32x2 u  = __builtin_elementwise_fma(ep, Kv, one2);
                f32x2 v  = __builtin_elementwise_fma(et, Kv, one2);
                f32x2 pr = u * v;
                float rD = __builtin_amdgcn_rcpf(pr.x * pr.y);
                f32x2 sw = {pr.y, pr.x};
                f32x2 s  = (de * Kv) * (sw * rD);
                unsigned h2;
                asm("v_cvt_pk_bf16_f32 %0, %1, %2" : "=v"(h2) : "v"(s.x), "v"(s.y));
                u2[j] = (int)h2;
            }
        }
        int4v t1 = {u1[0], u1[1], u1[2], u1[3]};
        int4v t2 = {u2[0], u2[1], u2[2], u2[3]};
        short8 A1 = __builtin_bit_cast(short8, t1);
        short8 A2 = __builtin_bit_cast(short8, t2);

        acc1 = __builtin_amdgcn_mfma_f32_16x16x32_bf16(A1, fb, acc1, 0, 0, 0);
        acc2 = __builtin_amdgcn_mfma_f32_16x16x32_bf16(A2, fb, acc2, 0, 0, 0);
        cnt  = __builtin_amdgcn_mfma_f32_16x16x32_bf16(ones, fb, cnt, 0, 0, 0);
    }
    __syncthreads();                  // all waves done reading mT

    // ---- epilogue: block reduce via LDS (reuse mT), then replicated atomics ----
    float* red  = (float*)mT;        // [4 waves][32 bins][10 cls] = 1280 floats
    float* redN = red + 1280;        // [4 waves][10]

    if (n15 < NCLS) {
        #pragma unroll
        for (int r = 0; r < 4; ++r) {
            int b1 = g * 4 + r;                  // C/D: row=(lane>>4)*4+reg, col=lane&15
            red[(w * 32 + b1) * NCLS + n15]      = acc1[r];
            red[(w * 32 + 16 + b1) * NCLS + n15] = acc2[r];
        }
    }
    if (lane < NCLS) redN[w * NCLS + lane] = cnt[0];   // row 0 of count tile
    __syncthreads();

    const int rep = chunk & (NREP - 1);
    float* gDr = gD + rep * (NBINS * NCLS);
    float* gNr = gN + rep * (2 * NCLS);
    const int nsel = (chunk < chunksPerN) ? 0 : 1;

    for (int i = tid; i < NBINS * NCLS; i += 256) {
        float s = red[i] + red[320 + i] + red[640 + i] + red[960 + i];
        atomicAdd(&gDr[i], s);
    }
    if (tid < NCLS) {
        float s = redN[tid] + redN[10 + tid] + redN[20 + tid] + redN[30 + tid];
        atomicAdd(&gNr[nsel * NCLS + tid], s);
    }
}

__global__ __launch_bounds__(512) void dvh_final(
    const float* __restrict__ gD, const float* __restrict__ gN, float* __restrict__ out)
{
    __shared__ float red[512];
    __shared__ float nvs[2 * NCLS];
    const int t = threadIdx.x;

    if (t < 2 * NCLS) {
        float s = 1.f;
        #pragma unroll
        for (int r = 0; r < NREP; ++r) s += gN[r * (2 * NCLS) + t];
        nvs[t] = s;
    }
    float d = 0.f;
    if (t < NBINS * NCLS) {
        #pragma unroll
        for (int r = 0; r < NREP; ++r) d += gD[r * (NBINS * NCLS) + t];
    }
    __syncthreads();

    float v = 0.f;
    if (t < NBINS * NCLS) {
        int c = t % NCLS;
        float nv0 = nvs[c], nv1 = nvs[NCLS + c];
        v = d * d * (1.f / (nv0 * nv0) + 1.f / (nv1 * nv1));
    }
    red[t] = v;
    __syncthreads();
    for (int s = 256; s > 0; s >>= 1) {
        if (t < s) red[t] += red[t + s];
        __syncthreads();
    }
    if (t == 0) out[0] = red[0] * (1.f / 1280.f);
}

extern "C" void kernel_launch(void* const* d_in, const int* in_sizes, int n_in,
                              void* d_out, int out_size, void* d_ws, size_t ws_size,
                              hipStream_t stream) {
    const float* pred = (const float*)d_in[0];
    const float* targ = (const float*)d_in[1];
    const float* mask = (const float*)d_in[2];
    float* gD = (float*)d_ws;                                    // NREP x 320 floats
    float* gN = (float*)((char*)d_ws + NREP * NBINS * NCLS * 4); // NREP x 20 floats

    hipMemsetAsync(d_ws, 0, NREP * (NBINS * NCLS + 2 * NCLS) * 4, stream);

    int totalVox    = in_sizes[0];           // N*V = 4194304
    int chunksTotal = totalVox / CHUNK;      // 4096
    int chunksPerN  = chunksTotal / 2;       // 2048

    dvh_main<<<chunksTotal, 256, 0, stream>>>(pred, targ, mask, gD, gN, chunksPerN);
    dvh_final<<<1, 512, 0, stream>>>(gD, gN, (float*)d_out);
}